// Round 7
// baseline (250.589 us; speedup 1.0000x reference)
//
#include <hip/hip_runtime.h>

#define B_   16
#define CIN  32
#define COUT 32
#define H_   256
#define W_   256
#define IN_ZP  3
#define OUT_ZP (-5)
#define HW (H_ * W_)
#define TH 8
#define TW 64
#define SW 72   // staged cols: gw = wt-4 .. wt+67
#define SH 10   // staged rows: gh = ht-1 .. ht+8

// pre-padded packed activation buffer xp in d_ws:
//   xp[b][cig][ph][pw], word = 4 packed int8 (ci = 4*cig .. 4*cig+3)
//   ph = gh+1 (gh in [-1,256]), pw = gw+4 (gw in [-4,259]); border = 0x03030303
#define XPH 258
#define XPW 264
#define XPQ 66                        // 16B quads per row
#define PLANE_W (XPH * XPW)           // 68112 words per (b,cig) plane
#define XP_WORDS (B_ * 8 * PLANE_W)   // 8,718,336 words = 34.87 MB
#define WS_TAB 2400                   // table words before xp
#define WS_NEED ((size_t)(WS_TAB + XP_WORDS) * 4)
#define NQ (B_ * 8 * XPH * XPQ)       // 2,179,584 output quads
#define PACK_BLOCKS 2176

// NOTE (round-4/5/6 finding): the harness re-poisons the 512 MB workspace each
// iteration with ~2 fillBufferAligned dispatches @ ~81 us = ~161 us FIXED
// overhead inside dur_us. Controllable budget = pack (~30 us, near BW floor)
// + fused (~57 us vs 27 us floor). Fused is the only remaining lever.

using i32x4  = __attribute__((ext_vector_type(4))) int;
using i32x16 = __attribute__((ext_vector_type(16))) int;

// ws layout (ints):
//   [0 .. 2303]    weight fragments: ws[(t*64+lane)*4+g], byte b =
//                  qweight[co=lane&31][ci=16*(lane>>5)+4g+b][tap t]
//   [2304 .. 2335] shifted bias
//   [2336 .. 2367] packed requant: isc | (frac_bits << 16)
//   [2400 .. ]     xp (packed padded activations), fast path only

// ---- kernel 1: prep (blocks 0..31) + activation pack (blocks 32..) ----
__global__ __launch_bounds__(256) void qconv_pack(const int* __restrict__ x,
                                                  const int* __restrict__ qw,
                                                  const int* __restrict__ qb,
                                                  const float* __restrict__ wscale,
                                                  int* __restrict__ ws) {
    const int bid = blockIdx.x;
    const int tid = threadIdx.x;
    if (bid < 32) {
        // ---- prep: weight fragments + bias/scale tables (unchanged math) ----
        __shared__ int red[4];
        const int co = bid;
        const int* wco = qw + co * (CIN * 9);
        int s = 0;
        for (int i = tid; i < CIN * 9; i += 256) s += wco[i];
        for (int off = 32; off; off >>= 1) s += __shfl_down(s, off, 64);
        if ((tid & 63) == 0) red[tid >> 6] = s;

        if (tid < 72) {
            int gidx = co * 72 + tid;
            int g    = gidx & 3;
            int lane = (gidx >> 2) & 63;
            int t    = gidx >> 8;
            int wco2 = lane & 31;
            int ci0  = 16 * (lane >> 5) + 4 * g;
            const int* base = qw + wco2 * (CIN * 9);
            int b0 = base[(ci0 + 0) * 9 + t] & 0xff;
            int b1 = base[(ci0 + 1) * 9 + t] & 0xff;
            int b2 = base[(ci0 + 2) * 9 + t] & 0xff;
            int b3 = base[(ci0 + 3) * 9 + t] & 0xff;
            ws[gidx] = b0 | (b1 << 8) | (b2 << 16) | (b3 << 24);
        }
        __syncthreads();
        if (tid == 0) {
            int wsum = red[0] + red[1] + red[2] + red[3];
            ws[2304 + co] = qb[co] - wsum * IN_ZP;
            float fs = (0.02f * wscale[co]) / 0.05f;
            float fb = floorf(log2f(127.0f / fs));
            int isc = (int)rintf(fs * exp2f(fb));  // half-to-even, matches jnp.round
            ws[2336 + co] = isc | (((int)fb) << 16);
        }
        return;
    }
    // ---- pack: streaming int32 -> padded packed int8x4 (branch-free body) ----
    int* __restrict__ xp = ws + WS_TAB;
    const int T = (PACK_BLOCKS) * 256;
    for (int q = (bid - 32) * 256 + tid; q < NQ; q += T) {
        int b   = q / (8 * XPH * XPQ);
        int r1  = q - b * (8 * XPH * XPQ);
        int cig = r1 / (XPH * XPQ);
        int r2  = r1 - cig * (XPH * XPQ);
        int ph  = r2 / XPQ;
        int cq  = r2 - ph * XPQ;
        int gh  = ph - 1;
        int gw0 = cq * 4 - 4;
        int ghc = min(H_ - 1, max(0, gh));
        int gwc = min(W_ - 4, max(0, gw0));
        const int* p = x + (b * CIN + cig * 4) * HW + ghc * W_ + gwc;
        i32x4 v0 = *(const i32x4*)(p);
        i32x4 v1 = *(const i32x4*)(p + HW);
        i32x4 v2 = *(const i32x4*)(p + 2 * HW);
        i32x4 v3 = *(const i32x4*)(p + 3 * HW);
        bool vh = (unsigned)gh < (unsigned)H_;
        i32x4 pk;
#pragma unroll
        for (int j = 0; j < 4; ++j) {
            int t = (v0[j] & 0xff) | ((v1[j] & 0xff) << 8) |
                    ((v2[j] & 0xff) << 16) | (v3[j] << 24);
            bool ok = vh && ((unsigned)(gw0 + j) < (unsigned)W_);
            pk[j] = ok ? t : 0x03030303;
        }
        *(i32x4*)(xp + 4 * q) = pk;   // dst word offset = 4q by construction
    }
}

// ---- kernel 2 (fast path): direct xp operand loads, weight frags in LDS ----
// Weight fragments (36 VGPRs persistent in rounds 0-6) now live in LDS,
// DMA'd once per block, one ds_read_b128 (lane-stride 16B, conflict-free,
// imm-offset) per MFMA. Persistent live set ~50 regs -> target <=64 VGPR ->
// 8 waves/SIMD -> whole 2048-block grid co-resident (was 5 -> two ragged
// rounds). __launch_bounds__(256) ONLY — no min-waves argument.
// HISTORY: (256,6)->VGPR 40 + 840MB scratch; (256,5)->VGPR 48 + 520MB scratch.
// gfx950 unified VGPR/AGPR file: a min-waves cap budgets arch VGPRs AND MFMA
// AGPRs together, starving arch allocation -> spill. Plain (256) never spilled.
__global__ __launch_bounds__(256) void qconv_fused(const int* __restrict__ ws,
                                                   int* __restrict__ out) {
    __shared__ __align__(16) int bfr[2304];    // weight fragments (9 KB)
    __shared__ __align__(16) int cons[64];     // sb[32] | packed (isc|fb<<16)[32]

    // bijective XCD-chunked swizzle: grid = 4*32*16 = 2048 = 8 XCD * 256.
    const int d  = blockIdx.x + 4 * blockIdx.y + 128 * blockIdx.z;
    const int w  = ((d & 7) << 8) | (d >> 3);
    const int tx = w & 3;
    const int ty = (w >> 2) & 31;
    const int tb = w >> 7;

    const int wt = tx * TW;
    const int ht = ty * TH;
    const int tid = threadIdx.x;
    const int lane = tid & 63, wv = tid >> 6;
    const int hh  = lane >> 5;
    const int pix = lane & 31;
    const int* __restrict__ xp = ws + WS_TAB;

    if (tid < 64) cons[tid] = ws[2304 + tid];

    // DMA the 9 KB fragment table into LDS: 9 x 1KB wave-chunks.
    // dst = wave-uniform base + lane*16 (global_load_lds write pattern);
    // src = ws + 4*(j*64+lane) -> LDS word 4*(j*64+lane): layout identical.
#pragma unroll
    for (int j = wv; j < 9; j += 4) {
        __builtin_amdgcn_global_load_lds(
            (const __attribute__((address_space(1))) void*)(ws + 4 * (j * 64 + lane)),
            (__attribute__((address_space(3))) void*)(bfr + j * 256),
            16, 0, 0);
    }
    __syncthreads();   // drains DMA (vmcnt) + cons write (lgkmcnt)

    // per-lane operand base: word(cig,rr,dw) for tile (r0,chunk) =
    //   xp[(rowbase + cig*XPH + r0+dh)*XPW + wt + chunk*32 + pix + 3 + dw]
    const int rowbase = (tb * 8) * XPH + ht;
    const int* xbase = xp + rowbase * XPW + wt + pix + 3;
    const i32x4* __restrict__ bls = (const i32x4*)bfr;

    // 4 M-tiles per wave; unroll 1 keeps the live set small.
#pragma unroll 1
    for (int i = 0; i < 4; ++i) {
        const int mt = wv * 4 + i;
        const int r0 = mt >> 1, chunk = mt & 1;
        const int* xt = xbase + (hh * 4) * PLANE_W + r0 * XPW + chunk * 32;
        i32x16 acc;
#pragma unroll
        for (int r = 0; r < 16; ++r) acc[r] = 0;
#pragma unroll
        for (int dh = 0; dh < 3; ++dh) {
#pragma unroll
            for (int dw = 0; dw < 3; ++dw) {
                i32x4 a;
#pragma unroll
                for (int g = 0; g < 4; ++g)
                    a[g] = xt[g * PLANE_W + dh * XPW + dw];
                i32x4 bf = bls[(dh * 3 + dw) * 64 + lane];   // ds_read_b128
                acc = __builtin_amdgcn_mfma_i32_32x32x32_i8(bf, a, acc, 0, 0, 0);
            }
        }
        // epilogue: D row = co = 4*hh + 8*rg + j, D col = pix -> coalesced
        // nontemporal stores (write-once; keep L2 for xp windows)
        int* op = out + (tb * COUT) * HW + (ht + r0) * W_ + wt + chunk * 32 + pix;
#pragma unroll
        for (int rg = 0; rg < 4; ++rg) {
            const int cb = 4 * hh + 8 * rg;
            i32x4 sb4 = *(const i32x4*)&cons[cb];
            i32x4 qf4 = *(const i32x4*)&cons[32 + cb];
#pragma unroll
            for (int j = 0; j < 4; ++j) {
                int q = qf4[j];
                int v = acc[rg * 4 + j] + sb4[j];
                v = (int)((unsigned)v * (unsigned)(q & 0xffff)) >> (q >> 16);
                v += OUT_ZP;
                v = min(127, max(-128, v));
                __builtin_nontemporal_store(v, op + (cb + j) * HW);
            }
        }
    }
}

// ---- fallback path (ws too small for xp): round-3 proven kernels ----
__global__ void qconv_prep_fb(const int* __restrict__ qw, const int* __restrict__ qb,
                              const float* __restrict__ wscale, int* __restrict__ ws) {
    const int co  = blockIdx.x;
    const int tid = threadIdx.x;
    __shared__ int red[4];
    const int* wco = qw + co * (CIN * 9);
    int s = 0;
    for (int i = tid; i < CIN * 9; i += 256) s += wco[i];
    for (int off = 32; off; off >>= 1) s += __shfl_down(s, off, 64);
    if ((tid & 63) == 0) red[tid >> 6] = s;
    if (tid < 72) {
        int gidx = blockIdx.x * 72 + tid;
        int g    = gidx & 3;
        int lane = (gidx >> 2) & 63;
        int t    = gidx >> 8;
        int wco2 = lane & 31;
        int ci0  = 16 * (lane >> 5) + 4 * g;
        const int* base = qw + wco2 * (CIN * 9);
        int b0 = base[(ci0 + 0) * 9 + t] & 0xff;
        int b1 = base[(ci0 + 1) * 9 + t] & 0xff;
        int b2 = base[(ci0 + 2) * 9 + t] & 0xff;
        int b3 = base[(ci0 + 3) * 9 + t] & 0xff;
        ws[gidx] = b0 | (b1 << 8) | (b2 << 16) | (b3 << 24);
    }
    __syncthreads();
    if (tid == 0) {
        int wsum = red[0] + red[1] + red[2] + red[3];
        ws[2304 + co] = qb[co] - wsum * IN_ZP;
        float fs = (0.02f * wscale[co]) / 0.05f;
        float fb = floorf(log2f(127.0f / fs));
        int isc = (int)rintf(fs * exp2f(fb));
        ws[2336 + co] = isc | (((int)fb) << 16);
    }
}

__device__ __forceinline__ void stage_item(int idx, int ht, int wt,
                                           const int* __restrict__ xb,
                                           int (*smem)[SH][SW]) {
    int cig = idx / 180;
    int rem = idx - cig * 180;
    int r   = rem / 18;
    int c4  = rem - r * 18;
    int gh  = ht - 1 + r;
    int gw0 = wt - 4 + c4 * 4;
    int ghc = min(H_ - 1, max(0, gh));
    int gwc = min(W_ - 4, max(0, gw0));
    const int* p = xb + (cig * 4) * HW + ghc * W_ + gwc;
    i32x4 v0 = *(const i32x4*)(p);
    i32x4 v1 = *(const i32x4*)(p + HW);
    i32x4 v2 = *(const i32x4*)(p + 2 * HW);
    i32x4 v3 = *(const i32x4*)(p + 3 * HW);
    bool vh = (unsigned)gh < (unsigned)H_;
    i32x4 pk;
#pragma unroll
    for (int j = 0; j < 4; ++j) {
        int t = (v0[j] & 0xff) | ((v1[j] & 0xff) << 8) |
                ((v2[j] & 0xff) << 16) | (v3[j] << 24);
        bool ok = vh && ((unsigned)(gw0 + j) < (unsigned)W_);
        pk[j] = ok ? t : 0x03030303;
    }
    *(i32x4*)&smem[cig][r][c4 * 4] = pk;
}

__global__ __launch_bounds__(256) void qconv_fused_fb(const int* __restrict__ x,
                                                      const int* __restrict__ ws,
                                                      int* __restrict__ out) {
    __shared__ int smem[8][SH][SW];
    __shared__ __align__(16) int cons[64];
    const int d  = blockIdx.x + 4 * blockIdx.y + 128 * blockIdx.z;
    const int w  = ((d & 7) << 8) | (d >> 3);
    const int tx = w & 3;
    const int ty = (w >> 2) & 31;
    const int tb = w >> 7;
    const int wt = tx * TW;
    const int ht = ty * TH;
    const int tid = threadIdx.x;
    const int* xb = x + tb * (CIN * HW);
    if (tid < 64) cons[tid] = ws[2304 + tid];
    stage_item(tid,        ht, wt, xb, smem);
    stage_item(tid + 256,  ht, wt, xb, smem);
    stage_item(tid + 512,  ht, wt, xb, smem);
    stage_item(tid + 768,  ht, wt, xb, smem);
    stage_item(tid + 1024, ht, wt, xb, smem);
    if (tid < 160) stage_item(tid + 1280, ht, wt, xb, smem);
    __syncthreads();
    const int lane = tid & 63, wv = tid >> 6;
    const int hh  = lane >> 5;
    const int pix = lane & 31;
    i32x4 wfrag[9];
    const i32x4* wsv = (const i32x4*)ws;
#pragma unroll
    for (int t = 0; t < 9; ++t) wfrag[t] = wsv[t * 64 + lane];
#pragma unroll
    for (int i = 0; i < 4; ++i) {
        const int mt = wv * 4 + i;
        const int r0 = mt >> 1, chunk = mt & 1;
        i32x16 acc;
#pragma unroll
        for (int r = 0; r < 16; ++r) acc[r] = 0;
#pragma unroll
        for (int t = 0; t < 9; ++t) {
            const int dh = t / 3, dw = t % 3;
            const int rr = r0 + dh;
            const int c  = chunk * 32 + pix + dw + 3;
            i32x4 a;
#pragma unroll
            for (int g = 0; g < 4; ++g) a[g] = smem[4 * hh + g][rr][c];
            acc = __builtin_amdgcn_mfma_i32_32x32x32_i8(wfrag[t], a, acc, 0, 0, 0);
        }
        int* op = out + (tb * COUT) * HW + (ht + r0) * W_ + wt + chunk * 32 + pix;
#pragma unroll
        for (int rg = 0; rg < 4; ++rg) {
            const int cb = 4 * hh + 8 * rg;
            i32x4 sb4 = *(const i32x4*)&cons[cb];
            i32x4 qf4 = *(const i32x4*)&cons[32 + cb];
#pragma unroll
            for (int j = 0; j < 4; ++j) {
                int q = qf4[j];
                int v = acc[rg * 4 + j] + sb4[j];
                v = (int)((unsigned)v * (unsigned)(q & 0xffff)) >> (q >> 16);
                v += OUT_ZP;
                v = min(127, max(-128, v));
                op[(cb + j) * HW] = v;
            }
        }
    }
}

extern "C" void kernel_launch(void* const* d_in, const int* in_sizes, int n_in,
                              void* d_out, int out_size, void* d_ws, size_t ws_size,
                              hipStream_t stream) {
    const int*   x   = (const int*)d_in[0];
    const int*   qw  = (const int*)d_in[1];
    const int*   qb  = (const int*)d_in[2];
    const float* wsc = (const float*)d_in[3];
    int* ws  = (int*)d_ws;
    int* out = (int*)d_out;
    dim3 grid(W_ / TW, H_ / TH, B_);

    if (ws_size >= WS_NEED) {
        qconv_pack<<<32 + PACK_BLOCKS, 256, 0, stream>>>(x, qw, qb, wsc, ws);
        qconv_fused<<<grid, 256, 0, stream>>>(ws, out);
    } else {
        qconv_prep_fb<<<32, 256, 0, stream>>>(qw, qb, wsc, ws);
        qconv_fused_fb<<<grid, 256, 0, stream>>>(x, ws, out);
    }
}

// Round 8
// 247.616 us; speedup vs baseline: 1.0120x; 1.0120x over previous
//
#include <hip/hip_runtime.h>

#define B_   16
#define CIN  32
#define COUT 32
#define H_   256
#define W_   256
#define IN_ZP  3
#define OUT_ZP (-5)
#define HW (H_ * W_)
#define TH 8
#define TW 64
#define SW 72   // staged cols: gw = wt-4 .. wt+67
#define SH 10   // staged rows: gh = ht-1 .. ht+8

// pre-padded packed activation buffer xp in d_ws:
//   xp[b][cig][ph][pw], word = 4 packed int8 (ci = 4*cig .. 4*cig+3)
//   ph = gh+1 (gh in [-1,256]), pw = gw+4 (gw in [-4,259]); border = 0x03030303
#define XPH 258
#define XPW 264
#define XPQ 66                        // 16B quads per row
#define PLANE_W (XPH * XPW)           // 68112 words per (b,cig) plane
#define XP_WORDS (B_ * 8 * PLANE_W)   // 8,718,336 words = 34.87 MB
#define WS_TAB 2400                   // table words before xp
#define WS_NEED ((size_t)(WS_TAB + XP_WORDS) * 4)
#define NQ (B_ * 8 * XPH * XPQ)       // 2,179,584 output quads
#define PACK_BLOCKS 2176

// NOTE (rounds 4-7 accounting): harness re-poisons the 512 MB workspace with
// ~2 fillBufferAligned @ ~81 us = ~163 us FIXED overhead inside dur_us
// (round-0 closes: fused 87 + fills 163 + prep ~ 252 total, ~0 slack).
// Controllable = pack (~30 us, near BW floor) + fused (~55 us vs 27 floor).
// Round 5->6: removing the whole staging phase moved fused only ~3 us =>
// fused is ISSUE-bound (per-tile VALU + quarter-rate v_mul_lo_u32 epilogue),
// not staging-latency-bound. This round: mad24 epilogue.

using i32x4  = __attribute__((ext_vector_type(4))) int;
using i32x16 = __attribute__((ext_vector_type(16))) int;

// ws layout (ints), fast path:
//   [0 .. 2303]    weight fragments: ws[(t*64+lane)*4+g], byte b =
//                  qweight[co=lane&31][ci=16*(lane>>5)+4g+b][tap t]
//   [2304 .. 2335] sbi = sb*isc + OUT_ZP*2^fb   (sb = qbias - wsum*IN_ZP)
//   [2336 .. 2367] isc
//   [2368 .. 2399] fb
//   [2400 .. ]     xp (packed padded activations)

// ---- kernel 1: prep (blocks 0..31) + activation pack (blocks 32..) ----
__global__ __launch_bounds__(256) void qconv_pack(const int* __restrict__ x,
                                                  const int* __restrict__ qw,
                                                  const int* __restrict__ qb,
                                                  const float* __restrict__ wscale,
                                                  int* __restrict__ ws) {
    const int bid = blockIdx.x;
    const int tid = threadIdx.x;
    if (bid < 32) {
        // ---- prep: weight fragments + requant tables ----
        __shared__ int red[4];
        const int co = bid;
        const int* wco = qw + co * (CIN * 9);
        int s = 0;
        for (int i = tid; i < CIN * 9; i += 256) s += wco[i];
        for (int off = 32; off; off >>= 1) s += __shfl_down(s, off, 64);
        if ((tid & 63) == 0) red[tid >> 6] = s;

        if (tid < 72) {
            int gidx = co * 72 + tid;
            int g    = gidx & 3;
            int lane = (gidx >> 2) & 63;
            int t    = gidx >> 8;
            int wco2 = lane & 31;
            int ci0  = 16 * (lane >> 5) + 4 * g;
            const int* base = qw + wco2 * (CIN * 9);
            int b0 = base[(ci0 + 0) * 9 + t] & 0xff;
            int b1 = base[(ci0 + 1) * 9 + t] & 0xff;
            int b2 = base[(ci0 + 2) * 9 + t] & 0xff;
            int b3 = base[(ci0 + 3) * 9 + t] & 0xff;
            ws[gidx] = b0 | (b1 << 8) | (b2 << 16) | (b3 << 24);
        }
        __syncthreads();
        if (tid == 0) {
            int wsum = red[0] + red[1] + red[2] + red[3];
            int sb   = qb[co] - wsum * IN_ZP;
            float fs = (0.02f * wscale[co]) / 0.05f;
            float fb = floorf(log2f(127.0f / fs));
            int isc  = (int)rintf(fs * exp2f(fb));  // half-to-even = jnp.round
            int ifb  = (int)fb;
            // exact fold: ((acc+sb)*isc + zp*2^fb) >> fb == ((acc+sb)*isc)>>fb + zp
            ws[2304 + co] = sb * isc + OUT_ZP * (1 << ifb);
            ws[2336 + co] = isc;
            ws[2368 + co] = ifb;
        }
        return;
    }
    // ---- pack: streaming int32 -> padded packed int8x4 (branch-free body) ----
    int* __restrict__ xp = ws + WS_TAB;
    const int T = (PACK_BLOCKS) * 256;
    for (int q = (bid - 32) * 256 + tid; q < NQ; q += T) {
        int b   = q / (8 * XPH * XPQ);
        int r1  = q - b * (8 * XPH * XPQ);
        int cig = r1 / (XPH * XPQ);
        int r2  = r1 - cig * (XPH * XPQ);
        int ph  = r2 / XPQ;
        int cq  = r2 - ph * XPQ;
        int gh  = ph - 1;
        int gw0 = cq * 4 - 4;
        int ghc = min(H_ - 1, max(0, gh));
        int gwc = min(W_ - 4, max(0, gw0));
        const int* p = x + (b * CIN + cig * 4) * HW + ghc * W_ + gwc;
        i32x4 v0 = *(const i32x4*)(p);
        i32x4 v1 = *(const i32x4*)(p + HW);
        i32x4 v2 = *(const i32x4*)(p + 2 * HW);
        i32x4 v3 = *(const i32x4*)(p + 3 * HW);
        bool vh = (unsigned)gh < (unsigned)H_;
        i32x4 pk;
#pragma unroll
        for (int j = 0; j < 4; ++j) {
            int t = (v0[j] & 0xff) | ((v1[j] & 0xff) << 8) |
                    ((v2[j] & 0xff) << 16) | (v3[j] << 24);
            bool ok = vh && ((unsigned)(gw0 + j) < (unsigned)W_);
            pk[j] = ok ? t : 0x03030303;
        }
        *(i32x4*)(xp + 4 * q) = pk;   // dst word offset = 4q by construction
    }
}

// ---- kernel 2 (fast path): direct xp operand loads, mad24 epilogue ----
// Round-6 structure (best: 248.0): no LDS staging, wfrag in VGPRs, NT stores.
// Epilogue per output: v_mad_i32_i24(acc, isc, sbi) >> fb, med3-clamp, store.
// 24-bit safety: |acc| <= 288*128*127 = 4.68e6 < 2^23; isc <= 127.
// __launch_bounds__(256) ONLY — no min-waves argument.
// HISTORY: (256,6)->VGPR 40 + 840MB scratch; (256,5)->VGPR 48 + 520MB scratch.
// gfx950 unified VGPR/AGPR file: a min-waves cap budgets arch VGPRs AND MFMA
// AGPRs together, starving arch allocation -> spill. Plain (256) never spilled.
// Round-7 lesson: weight frags in LDS (ds_read per MFMA) was -2.5 us. Keep regs.
__global__ __launch_bounds__(256) void qconv_fused(const int* __restrict__ ws,
                                                   int* __restrict__ out) {
    __shared__ __align__(16) int cons[96];  // sbi[32] | isc[32] | fb[32]

    // bijective XCD-chunked swizzle: grid = 4*32*16 = 2048 = 8 XCD * 256.
    const int d  = blockIdx.x + 4 * blockIdx.y + 128 * blockIdx.z;
    const int w  = ((d & 7) << 8) | (d >> 3);
    const int tx = w & 3;
    const int ty = (w >> 2) & 31;
    const int tb = w >> 7;

    const int wt = tx * TW;
    const int ht = ty * TH;
    const int tid = threadIdx.x;
    const int lane = tid & 63, wv = tid >> 6;
    const int hh  = lane >> 5;
    const int pix = lane & 31;
    const int* __restrict__ xp = ws + WS_TAB;

    if (tid < 96) cons[tid] = ws[2304 + tid];

    i32x4 wfrag[9];
    const i32x4* wsv = (const i32x4*)ws;
#pragma unroll
    for (int t = 0; t < 9; ++t) wfrag[t] = wsv[t * 64 + lane];

    __syncthreads();   // cons visible to all

    // per-lane operand base: word(cig,rr,dw) for tile (r0,chunk) =
    //   xp[(rowbase + cig*XPH + r0+dh)*XPW + wt + chunk*32 + pix + 3 + dw]
    const int rowbase = (tb * 8) * XPH + ht;
    const int* xbase = xp + rowbase * XPW + wt + pix + 3;

    // 4 M-tiles per wave; unroll 1 keeps the live set small.
#pragma unroll 1
    for (int i = 0; i < 4; ++i) {
        const int mt = wv * 4 + i;
        const int r0 = mt >> 1, chunk = mt & 1;
        const int* xt = xbase + (hh * 4) * PLANE_W + r0 * XPW + chunk * 32;
        i32x16 acc;
#pragma unroll
        for (int r = 0; r < 16; ++r) acc[r] = 0;
#pragma unroll
        for (int dh = 0; dh < 3; ++dh) {
#pragma unroll
            for (int dw = 0; dw < 3; ++dw) {
                i32x4 a;
#pragma unroll
                for (int g = 0; g < 4; ++g)
                    a[g] = xt[g * PLANE_W + dh * XPW + dw];
                acc = __builtin_amdgcn_mfma_i32_32x32x32_i8(
                          wfrag[dh * 3 + dw], a, acc, 0, 0, 0);
            }
        }
        // epilogue: D row = co = 4*hh + 8*rg + j, D col = pix -> coalesced
        // nontemporal stores (write-once; keep L2 for xp windows)
        int* op = out + (tb * COUT) * HW + (ht + r0) * W_ + wt + chunk * 32 + pix;
#pragma unroll
        for (int rg = 0; rg < 4; ++rg) {
            const int cb = 4 * hh + 8 * rg;
            i32x4 sbi4 = *(const i32x4*)&cons[cb];
            i32x4 isc4 = *(const i32x4*)&cons[32 + cb];
            i32x4 fb4  = *(const i32x4*)&cons[64 + cb];
#pragma unroll
            for (int j = 0; j < 4; ++j) {
                int v = (__mul24(acc[rg * 4 + j], isc4[j]) + sbi4[j]) >> fb4[j];
                v = min(127, max(-128, v));   // -> v_med3_i32
                __builtin_nontemporal_store(v, op + (cb + j) * HW);
            }
        }
    }
}

// ---- fallback path (ws too small for xp): round-3 proven kernels ----
__global__ void qconv_prep_fb(const int* __restrict__ qw, const int* __restrict__ qb,
                              const float* __restrict__ wscale, int* __restrict__ ws) {
    const int co  = blockIdx.x;
    const int tid = threadIdx.x;
    __shared__ int red[4];
    const int* wco = qw + co * (CIN * 9);
    int s = 0;
    for (int i = tid; i < CIN * 9; i += 256) s += wco[i];
    for (int off = 32; off; off >>= 1) s += __shfl_down(s, off, 64);
    if ((tid & 63) == 0) red[tid >> 6] = s;
    if (tid < 72) {
        int gidx = blockIdx.x * 72 + tid;
        int g    = gidx & 3;
        int lane = (gidx >> 2) & 63;
        int t    = gidx >> 8;
        int wco2 = lane & 31;
        int ci0  = 16 * (lane >> 5) + 4 * g;
        const int* base = qw + wco2 * (CIN * 9);
        int b0 = base[(ci0 + 0) * 9 + t] & 0xff;
        int b1 = base[(ci0 + 1) * 9 + t] & 0xff;
        int b2 = base[(ci0 + 2) * 9 + t] & 0xff;
        int b3 = base[(ci0 + 3) * 9 + t] & 0xff;
        ws[gidx] = b0 | (b1 << 8) | (b2 << 16) | (b3 << 24);
    }
    __syncthreads();
    if (tid == 0) {
        int wsum = red[0] + red[1] + red[2] + red[3];
        ws[2304 + co] = qb[co] - wsum * IN_ZP;
        float fs = (0.02f * wscale[co]) / 0.05f;
        float fb = floorf(log2f(127.0f / fs));
        int isc = (int)rintf(fs * exp2f(fb));
        ws[2336 + co] = isc | (((int)fb) << 16);
    }
}

__device__ __forceinline__ void stage_item(int idx, int ht, int wt,
                                           const int* __restrict__ xb,
                                           int (*smem)[SH][SW]) {
    int cig = idx / 180;
    int rem = idx - cig * 180;
    int r   = rem / 18;
    int c4  = rem - r * 18;
    int gh  = ht - 1 + r;
    int gw0 = wt - 4 + c4 * 4;
    int ghc = min(H_ - 1, max(0, gh));
    int gwc = min(W_ - 4, max(0, gw0));
    const int* p = xb + (cig * 4) * HW + ghc * W_ + gwc;
    i32x4 v0 = *(const i32x4*)(p);
    i32x4 v1 = *(const i32x4*)(p + HW);
    i32x4 v2 = *(const i32x4*)(p + 2 * HW);
    i32x4 v3 = *(const i32x4*)(p + 3 * HW);
    bool vh = (unsigned)gh < (unsigned)H_;
    i32x4 pk;
#pragma unroll
    for (int j = 0; j < 4; ++j) {
        int t = (v0[j] & 0xff) | ((v1[j] & 0xff) << 8) |
                ((v2[j] & 0xff) << 16) | (v3[j] << 24);
        bool ok = vh && ((unsigned)(gw0 + j) < (unsigned)W_);
        pk[j] = ok ? t : 0x03030303;
    }
    *(i32x4*)&smem[cig][r][c4 * 4] = pk;
}

__global__ __launch_bounds__(256) void qconv_fused_fb(const int* __restrict__ x,
                                                      const int* __restrict__ ws,
                                                      int* __restrict__ out) {
    __shared__ int smem[8][SH][SW];
    __shared__ __align__(16) int cons[64];
    const int d  = blockIdx.x + 4 * blockIdx.y + 128 * blockIdx.z;
    const int w  = ((d & 7) << 8) | (d >> 3);
    const int tx = w & 3;
    const int ty = (w >> 2) & 31;
    const int tb = w >> 7;
    const int wt = tx * TW;
    const int ht = ty * TH;
    const int tid = threadIdx.x;
    const int* xb = x + tb * (CIN * HW);
    if (tid < 64) cons[tid] = ws[2304 + tid];
    stage_item(tid,        ht, wt, xb, smem);
    stage_item(tid + 256,  ht, wt, xb, smem);
    stage_item(tid + 512,  ht, wt, xb, smem);
    stage_item(tid + 768,  ht, wt, xb, smem);
    stage_item(tid + 1024, ht, wt, xb, smem);
    if (tid < 160) stage_item(tid + 1280, ht, wt, xb, smem);
    __syncthreads();
    const int lane = tid & 63, wv = tid >> 6;
    const int hh  = lane >> 5;
    const int pix = lane & 31;
    i32x4 wfrag[9];
    const i32x4* wsv = (const i32x4*)ws;
#pragma unroll
    for (int t = 0; t < 9; ++t) wfrag[t] = wsv[t * 64 + lane];
#pragma unroll
    for (int i = 0; i < 4; ++i) {
        const int mt = wv * 4 + i;
        const int r0 = mt >> 1, chunk = mt & 1;
        i32x16 acc;
#pragma unroll
        for (int r = 0; r < 16; ++r) acc[r] = 0;
#pragma unroll
        for (int t = 0; t < 9; ++t) {
            const int dh = t / 3, dw = t % 3;
            const int rr = r0 + dh;
            const int c  = chunk * 32 + pix + dw + 3;
            i32x4 a;
#pragma unroll
            for (int g = 0; g < 4; ++g) a[g] = smem[4 * hh + g][rr][c];
            acc = __builtin_amdgcn_mfma_i32_32x32x32_i8(wfrag[t], a, acc, 0, 0, 0);
        }
        int* op = out + (tb * COUT) * HW + (ht + r0) * W_ + wt + chunk * 32 + pix;
#pragma unroll
        for (int rg = 0; rg < 4; ++rg) {
            const int cb = 4 * hh + 8 * rg;
            i32x4 sb4 = *(const i32x4*)&cons[cb];
            i32x4 qf4 = *(const i32x4*)&cons[32 + cb];
#pragma unroll
            for (int j = 0; j < 4; ++j) {
                int q = qf4[j];
                int v = acc[rg * 4 + j] + sb4[j];
                v = (int)((unsigned)v * (unsigned)(q & 0xffff)) >> (q >> 16);
                v += OUT_ZP;
                v = min(127, max(-128, v));
                op[(cb + j) * HW] = v;
            }
        }
    }
}

extern "C" void kernel_launch(void* const* d_in, const int* in_sizes, int n_in,
                              void* d_out, int out_size, void* d_ws, size_t ws_size,
                              hipStream_t stream) {
    const int*   x   = (const int*)d_in[0];
    const int*   qw  = (const int*)d_in[1];
    const int*   qb  = (const int*)d_in[2];
    const float* wsc = (const float*)d_in[3];
    int* ws  = (int*)d_ws;
    int* out = (int*)d_out;
    dim3 grid(W_ / TW, H_ / TH, B_);

    if (ws_size >= WS_NEED) {
        qconv_pack<<<32 + PACK_BLOCKS, 256, 0, stream>>>(x, qw, qb, wsc, ws);
        qconv_fused<<<grid, 256, 0, stream>>>(ws, out);
    } else {
        qconv_prep_fb<<<32, 256, 0, stream>>>(qw, qb, wsc, ws);
        qconv_fused_fb<<<grid, 256, 0, stream>>>(x, ws, out);
    }
}